// Round 16
// baseline (96.986 us; speedup 1.0000x reference)
//
#include <hip/hip_runtime.h>
#include <math.h>

// CTC loss forward: T=1024, N=128, C=256, S=64, L=2S+1=129, blank=0.
constexpr int kT = 1024;
constexpr int kN = 128;
constexpr int kC = 256;
constexpr float NEGV = -1e30f;
constexpr int kRow = 260;            // floats per t4-group: 65 states x 4 t's
constexpr int kRowB = kRow * 4;      // 1040 bytes
constexpr int kCH = 32;              // t-steps per chunk per direction
constexpr int kNCH = 512 / kCH;      // 16 chunks per direction
constexpr int kChF = 8 * kRow;       // 2080 floats per chunk (8 t4-groups)
constexpr int kChB = kChF * 4;       // 8320 bytes
constexpr float LOG2E = 1.4426950408889634f;
constexpr float LN2 = 0.6931471805599453f;

using f32x4 = __attribute__((ext_vector_type(4))) float;

#if __has_builtin(__builtin_amdgcn_exp2f)
#define EXP2(x) __builtin_amdgcn_exp2f(x)
#else
#define EXP2(x) exp2f(x)
#endif
#if __has_builtin(__builtin_amdgcn_logf)
#define LOG2(x) __builtin_amdgcn_logf(x)
#else
#define LOG2(x) log2f(x)
#endif

struct TrueT { static constexpr bool value = true; };
struct FalseT { static constexpr bool value = false; };

__device__ __forceinline__ float lse2_2(float a, float b) {  // log2(2^a + 2^b)
    const float m = fmaxf(a, b);
    const float d = fminf(a, b) - m;
    return m + LOG2(1.0f + EXP2(d));
}

__device__ __forceinline__ float lse2_e(float a, float b) {  // ln(e^a + e^b)
    const float m = fmaxf(a, b);
    return m + __logf(1.0f + __expf(fminf(a, b) - m));
}

__device__ __forceinline__ float lse3_e(float a, float b, float c) {
    const float m = fmaxf(fmaxf(a, b), c);
    return m + __logf(__expf(a - m) + __expf(b - m) + __expf(c - m));
}

__device__ __forceinline__ unsigned lds_addr(const void* p) {
    return (unsigned)(unsigned long long)(const __attribute__((address_space(3))) void*)p;
}

// Kernel 1: per-row logsumexp over C=256. GATHER mode: block = (n, t4) covers
// 4 consecutive t for one n; writes BASE-2 log-probs in blocked-transposed
// layout lpg[n][t4][s][j] (s=0 blank, s=1+k label k; j=t&3), coalesced via LDS.
template <bool GATHER>
__global__ __launch_bounds__(256) void k_lse(const float* __restrict__ logits,
                                             const int* __restrict__ y,
                                             float* __restrict__ lpg,
                                             float* __restrict__ lse_out) {
    __shared__ float srow[4][kC];
    __shared__ float sT[4][65];
    const int w = threadIdx.x >> 6;
    const int lane = threadIdx.x & 63;
    const int n = blockIdx.x & (kN - 1);
    const int t4 = blockIdx.x >> 7;
    const int t = t4 * 4 + w;
    const int row = t * kN + n;

    const float4 v = reinterpret_cast<const float4*>(logits + (size_t)row * kC)[lane];
    float m = fmaxf(fmaxf(v.x, v.y), fmaxf(v.z, v.w));
#pragma unroll
    for (int o = 32; o > 0; o >>= 1) m = fmaxf(m, __shfl_xor(m, o));
    float s = __expf(v.x - m) + __expf(v.y - m) + __expf(v.z - m) + __expf(v.w - m);
#pragma unroll
    for (int o = 32; o > 0; o >>= 1) s += __shfl_xor(s, o);

    if (GATHER) {
        const float log2s = LOG2(s);
        float* sr = srow[w];
        reinterpret_cast<float4*>(sr)[lane] = v;
        const int cls = y[(n << 6) + lane];  // labels in [1, C)
        sT[w][1 + lane] = (sr[cls] - m) * LOG2E - log2s;
        if (lane == 0) sT[w][0] = (v.x - m) * LOG2E - log2s;  // blank
        __syncthreads();
        float* op = lpg + (size_t)n * (kT / 4) * kRow + (size_t)t4 * kRow;
        const int tid = threadIdx.x;
        op[tid] = sT[tid & 3][tid >> 2];            // idx = s*4 + j
        if (tid < 4) op[256 + tid] = sT[tid][64];   // s = 64, j = tid
    } else {
        if (lane == 0) lse_out[row] = m + __logf(s);
    }
}

// One DP step, log2 domain (validated r7/r11). Works for BOTH directions:
// fwd: A,B = alpha[2l], alpha[2l+1]; C = alpha[128] (lane 0); shuffle = B[l-1],
//      wrap lane0 <- B[63].
// bwd (reversed lane map): A,B = beta[128-2l], beta[127-2l]; C = beta[0]
//      (lane 0); identical shuffle/boundary structure (exact mirror).
template <bool FRZ>
__device__ __forceinline__ void dp_step(float& A, float& B, float& C,
                                        float lpb, float lpy, bool skip,
                                        int lgrp, int l, bool commit) {
    const int bi = __float_as_int(B);
    const int b15 = __builtin_amdgcn_readlane(bi, 15);
    const int b31 = __builtin_amdgcn_readlane(bi, 31);
    const int b47 = __builtin_amdgcn_readlane(bi, 47);
    const int b63 = __builtin_amdgcn_readlane(bi, 63);
    const int bndi = (lgrp == 0) ? b63 : (lgrp == 1) ? b15 : (lgrp == 2) ? b31 : b47;
    const float am1 = __int_as_float(__builtin_amdgcn_update_dpp(
        bndi, bi, 0x111 /*row_shr:1*/, 0xF, 0xF, false));
    const float am1s = skip ? am1 : NEGV;
    // nB = lpy + lse3(B, A, am1s): med3 2-exp form
    const float x = fmaxf(B, A), yv = fminf(B, A);
    const float mB = fmaxf(x, am1s);
    const float dB1 = fmaxf(yv, fminf(x, am1s)) - mB;  // med - max
    const float dB2 = fminf(yv, am1s) - mB;            // min - max
    const float nB = (lpy + mB) + LOG2(1.0f + (EXP2(dB1) + EXP2(dB2)));
    // even-state / extra-state share one lse2 (lane 0's slot computes C)
    const float u = (l == 0) ? C : A;
    const float mA = fmaxf(u, am1);
    const float lseA = mA + LOG2(1.0f + EXP2(fminf(u, am1) - mA));
    const float nA = lpb + ((l == 0) ? A : lseA);
    const float nC = lpb + lseA;  // meaningful at lane 0 only
    if (FRZ) {
        A = commit ? nA : A;
        B = commit ? nB : B;
        C = commit ? nC : C;
    } else {
        A = nA; B = nB; C = nC;
    }
}

// Chunk-load discipline: all 16 ds_read_b128 issued up-front (volatile asm,
// program-ordered), each group's consumption gated by a counted lgkmcnt wait
// that is DATAFLOW-TIED to the loaded registers ("+v") — no sched_barrier, no
// "memory" clobber, so independent VALU schedules freely. DS returns in-order.
#define DSR(dst, addr) asm volatile("ds_read_b128 %0, %1" : "=v"(dst) : "v"(addr))
#define DSW(NLIT, QA, QB) \
    asm volatile("s_waitcnt lgkmcnt(" #NLIT ")" : "+v"(QA), "+v"(QB))

// Kernel 2: split forward/backward DP. One block per batch item, 4 waves:
// w0 = alpha (t=1..511), w1 = beta (t=1023..512, reversed lane map), w2 stages
// the fwd lp stream, w3 the bwd stream. Merge:
// nll = -lse_s(alpha_511[s] + gamma_511[s]).
__global__ __launch_bounds__(256) void k_dp_split(const float* __restrict__ lpg,
                                                  const int* __restrict__ y,
                                                  const int* __restrict__ xlens,
                                                  const int* __restrict__ ylens,
                                                  float* __restrict__ nll_out) {
    __shared__ alignas(16) float sbf[2][kChF];
    __shared__ alignas(16) float sbb[2][kChF];
    __shared__ float st_f[130];
    __shared__ float st_b[130];
    const int n = blockIdx.x;
    const int wid = threadIdx.x >> 6;
    const int l = threadIdx.x & 63;
    const int lgrp = l >> 4;
    const char* src = (const char*)(lpg + (size_t)n * (kT / 4) * kRow);

    auto stage = [&](int c, int b, bool isF) {
        const long off = isF ? (long)c * kChB : (long)(256 - 8 * (c + 1)) * kRowB;
        const char* gs = src + off;
        char* ls = (char*)(isF ? &sbf[b][0] : &sbb[b][0]);
#pragma unroll
        for (int r = 0; r < 9; ++r) {
            const int wi = r * 64;  // wave-uniform word index; kChB/16 = 520 words
            if (wi + l < kChB / 16) {
                __builtin_amdgcn_global_load_lds(
                    (const __attribute__((address_space(1))) void*)(gs + (size_t)(wi + l) * 16),
                    (__attribute__((address_space(3))) void*)(ls + (size_t)wi * 16), 16, 0, 0);
            }
        }
    };

    if (wid >= 2) stage(0, 0, wid == 2);
    __syncthreads();

    const int yl = ylens[n];
    const int xl = xlens[n];

    if (wid == 0) {
        // ---------------- FORWARD: alpha, t = 1..511 ----------------
        const int ycur = y[(n << 6) + l];
        const int yprev = __shfl_up(ycur, 1);
        const bool skip = (l >= 1) && (ycur != yprev);
        float aA = (l == 0) ? sbf[0][0] : NEGV;  // lp[t=0][s=0]
        float aB = (l == 0) ? sbf[0][4] : NEGV;  // lp[t=0][s=1]
        float aC = NEGV;

        for (int c = 0; c < kNCH; ++c) {
            const float* B = sbf[c & 1];
            const int tb0 = c * kCH;
            auto body = [&](auto frzc) {
                constexpr bool FRZV = decltype(frzc)::value;
                const unsigned apb = lds_addr(&B[0]);
                const unsigned apy = lds_addr(&B[4 + 4 * l]);
                f32x4 qb0, qb1, qb2, qb3, qb4, qb5, qb6, qb7;
                f32x4 qy0, qy1, qy2, qy3, qy4, qy5, qy6, qy7;
                DSR(qb0, apb + 0u * kRowB); DSR(qy0, apy + 0u * kRowB);
                DSR(qb1, apb + 1u * kRowB); DSR(qy1, apy + 1u * kRowB);
                DSR(qb2, apb + 2u * kRowB); DSR(qy2, apy + 2u * kRowB);
                DSR(qb3, apb + 3u * kRowB); DSR(qy3, apy + 3u * kRowB);
                DSR(qb4, apb + 4u * kRowB); DSR(qy4, apy + 4u * kRowB);
                DSR(qb5, apb + 5u * kRowB); DSR(qy5, apy + 5u * kRowB);
                DSR(qb6, apb + 6u * kRowB); DSR(qy6, apy + 6u * kRowB);
                DSR(qb7, apb + 7u * kRowB); DSR(qy7, apy + 7u * kRowB);
#define FG(G, NLIT, QB, QY)                                                  \
    do {                                                                     \
        DSW(NLIT, QB, QY);                                                   \
        const int t0_ = tb0 + 4 * (G);                                       \
        dp_step<FRZV>(aA, aB, aC, QB.x, QY.x, skip, lgrp, l,                 \
                      (t0_ + 0 > 0) & (t0_ + 0 < xl));                       \
        dp_step<FRZV>(aA, aB, aC, QB.y, QY.y, skip, lgrp, l,                 \
                      (t0_ + 1 > 0) & (t0_ + 1 < xl));                       \
        dp_step<FRZV>(aA, aB, aC, QB.z, QY.z, skip, lgrp, l,                 \
                      (t0_ + 2 > 0) & (t0_ + 2 < xl));                       \
        dp_step<FRZV>(aA, aB, aC, QB.w, QY.w, skip, lgrp, l,                 \
                      (t0_ + 3 > 0) & (t0_ + 3 < xl));                       \
    } while (0)
                FG(0, 14, qb0, qy0);
                FG(1, 12, qb1, qy1);
                FG(2, 10, qb2, qy2);
                FG(3, 8, qb3, qy3);
                FG(4, 6, qb4, qy4);
                FG(5, 4, qb5, qy5);
                FG(6, 2, qb6, qy6);
                FG(7, 0, qb7, qy7);
#undef FG
            };
            if (c == 0 || xl < 512) body(TrueT{});
            else body(FalseT{});
            __syncthreads();
        }
        st_f[2 * l] = aA;
        st_f[2 * l + 1] = aB;
        if (l == 0) st_f[128] = aC;
        __syncthreads();

        // ---------------- MERGE ----------------
        const float v0 = st_f[l] + st_b[l];
        const float v1 = st_f[64 + l] + st_b[64 + l];
        const float v2 = (l == 0) ? (st_f[128] + st_b[128]) : NEGV;
        float mm = fmaxf(fmaxf(v0, v1), v2);
#pragma unroll
        for (int o = 32; o > 0; o >>= 1) mm = fmaxf(mm, __shfl_xor(mm, o));
        float sm = EXP2(v0 - mm) + EXP2(v1 - mm) + EXP2(v2 - mm);
#pragma unroll
        for (int o = 32; o > 0; o >>= 1) sm += __shfl_xor(sm, o);
        if (l == 0) {
            float nll;
            if (xl <= 512) {  // beta segment empty: read frozen alpha directly
                nll = -lse2_2(st_f[2 * yl], st_f[2 * yl - 1]) * LN2;
            } else {
                nll = -(mm + LOG2(sm)) * LN2;
            }
            if (!(isfinite(nll) && nll < 1e29f)) nll = 0.0f;  // zero_infinity
            nll_out[n] = nll / (float)yl;
        }
    } else if (wid == 1) {
        // ---------------- BACKWARD: beta, t = 1023..512 (reversed lanes) ----
        // lane l owns states (128-2l, 127-2l); state 0 in lane 0's extra slot.
        const int ycb = y[(n << 6) + 63 - l];     // label of state 127-2l
        const int yup = __shfl_up(ycb, 1);        // y[64-l]
        const bool skipb = (l >= 1) && (ycb != yup);
        const int ls = 64 - yl;                   // seed lane (yl=64 -> 0)
        float bA = NEGV, bB = NEGV, b0 = NEGV;

        for (int c = 0; c < kNCH; ++c) {
            const float* B = sbb[c & 1];
            const int ttop = 1023 - kCH * c;      // t of first (descending) slot
            auto body = [&](auto frzc) {
                constexpr bool FRZV = decltype(frzc)::value;
                const unsigned apb = lds_addr(&B[0]);
                const unsigned apy = lds_addr(&B[256 - 4 * l]);
                f32x4 qb0, qb1, qb2, qb3, qb4, qb5, qb6, qb7;
                f32x4 qy0, qy1, qy2, qy3, qy4, qy5, qy6, qy7;
                // group G consumes t4-block (7-G): descending t
                DSR(qb0, apb + 7u * kRowB); DSR(qy0, apy + 7u * kRowB);
                DSR(qb1, apb + 6u * kRowB); DSR(qy1, apy + 6u * kRowB);
                DSR(qb2, apb + 5u * kRowB); DSR(qy2, apy + 5u * kRowB);
                DSR(qb3, apb + 4u * kRowB); DSR(qy3, apy + 4u * kRowB);
                DSR(qb4, apb + 3u * kRowB); DSR(qy4, apy + 3u * kRowB);
                DSR(qb5, apb + 2u * kRowB); DSR(qy5, apy + 2u * kRowB);
                DSR(qb6, apb + 1u * kRowB); DSR(qy6, apy + 1u * kRowB);
                DSR(qb7, apb + 0u * kRowB); DSR(qy7, apy + 0u * kRowB);
#define BSTEP(LPB, LPY, T)                                                   \
    do {                                                                     \
        dp_step<FRZV>(bA, bB, b0, (LPB), (LPY), skipb, lgrp, l,              \
                      ((T) >= 512) & ((T) <= xl - 2));                       \
        if (FRZV) { /* seed beta_{xl-1} in-stream */                         \
            const bool ss = ((T) == xl - 1);                                 \
            bA = ss ? ((l == ls) ? (LPB) : NEGV) : bA;                       \
            bB = ss ? ((l == ls) ? (LPY) : NEGV) : bB;                       \
            b0 = ss ? NEGV : b0;                                             \
        }                                                                    \
    } while (0)
#define BG(G, NLIT, QB, QY)                                                  \
    do {                                                                     \
        DSW(NLIT, QB, QY);                                                   \
        BSTEP(QB.w, QY.w, ttop - (4 * (G) + 0));                             \
        BSTEP(QB.z, QY.z, ttop - (4 * (G) + 1));                             \
        BSTEP(QB.y, QY.y, ttop - (4 * (G) + 2));                             \
        BSTEP(QB.x, QY.x, ttop - (4 * (G) + 3));                             \
    } while (0)
                BG(0, 14, qb0, qy0);
                BG(1, 12, qb1, qy1);
                BG(2, 10, qb2, qy2);
                BG(3, 8, qb3, qy3);
                BG(4, 6, qb4, qy4);
                BG(5, 4, qb5, qy5);
                BG(6, 2, qb6, qy6);
                BG(7, 0, qb7, qy7);
#undef BG
#undef BSTEP
            };
            if (c == 0 || xl < kT) body(TrueT{});
            else body(FalseT{});
            __syncthreads();
        }
        // gamma_511[s] = lse(beta[s], beta[s+1], allow? beta[s+2]) = one more
        // mirror step with lp = 0 (unconditional).
        dp_step<false>(bA, bB, b0, 0.0f, 0.0f, skipb, lgrp, l, true);
        st_b[128 - 2 * l] = bA;
        st_b[127 - 2 * l] = bB;
        if (l == 0) st_b[0] = b0;
        __syncthreads();
    } else {
        // ---------------- STAGERS (w2 = fwd, w3 = bwd) ----------------
        const bool isF = (wid == 2);
        for (int c = 0; c < kNCH; ++c) {
            if (c + 1 < kNCH) stage(c + 1, (c + 1) & 1, isF);
            __syncthreads();
        }
        __syncthreads();  // match the post-loop barrier
    }
}

// Fallback DP (no gather workspace): log-domain, gathers raw logits. Slow but correct.
template <int PFB>
__global__ __launch_bounds__(64) void k_dp_fb(const float* __restrict__ logits,
                                              const float* __restrict__ lsearr,
                                              const int* __restrict__ y,
                                              const int* __restrict__ xlens,
                                              const int* __restrict__ ylens,
                                              float* __restrict__ nll_out) {
    const int n = blockIdx.x;
    const int l = threadIdx.x;
    const int yl = ylens[n];
    const int xl = xlens[n];
    const int ycur = y[(n << 6) + l];
    const int yprev = __shfl_up(ycur, 1);
    const bool skip = (l >= 1) && (ycur != yprev);

    auto load_lp = [&](int t, float& lpb, float& lpy) {
        const float* p = logits + ((size_t)t * kN + n) * kC;
        const float d = lsearr[t * kN + n];
        lpb = p[0] - d;
        lpy = p[ycur] - d;
    };

    float lpb0, lpy0;
    load_lp(0, lpb0, lpy0);
    float aA = (l == 0) ? lpb0 : NEGV;
    float aB = (l == 0) ? lpy0 : NEGV;
    float aC = NEGV;

    float pb[PFB], py[PFB];
#pragma unroll
    for (int k = 0; k < PFB; ++k) load_lp(1 + k, pb[k], py[k]);

    for (int tb = 1; tb < kT; tb += PFB) {
#pragma unroll
        for (int k = 0; k < PFB; ++k) {
            const int t = tb + k;
            if (t < kT) {
                const float lpb = pb[k], lpy = py[k];
                if (t + PFB < kT) load_lp(t + PFB, pb[k], py[k]);
                float am1 = __shfl_up(aB, 1);
                if (l == 0) am1 = NEGV;
                const float nA = lpb + lse2_e(aA, am1);
                const float nB = lpy + lse3_e(aB, aA, skip ? am1 : NEGV);
                float nC = aC;
                if (l == 63) nC = lpb + lse2_e(aC, aB);
                if (t < xl) { aA = nA; aB = nB; aC = nC; }
            }
        }
    }

    __shared__ float st[130];
    st[2 * l] = aA;
    st[2 * l + 1] = aB;
    if (l == 63) st[128] = aC;
    __syncthreads();
    if (l == 0) {
        const int end = 2 * yl;
        float nll = -lse2_e(st[end], st[end - 1]);
        if (!(isfinite(nll) && nll < 1e29f)) nll = 0.0f;
        nll_out[n] = nll / (float)yl;
    }
}

__global__ __launch_bounds__(128) void k_reduce(const float* __restrict__ nll,
                                                float* __restrict__ out) {
    const int tid = threadIdx.x;
    float v = nll[tid];
#pragma unroll
    for (int o = 32; o > 0; o >>= 1) v += __shfl_xor(v, o);
    __shared__ float partial[2];
    if ((tid & 63) == 0) partial[tid >> 6] = v;
    __syncthreads();
    if (tid == 0) out[0] = (partial[0] + partial[1]) * (1.0f / (float)kN);
}

extern "C" void kernel_launch(void* const* d_in, const int* in_sizes, int n_in,
                              void* d_out, int out_size, void* d_ws, size_t ws_size,
                              hipStream_t stream) {
    const float* logits = (const float*)d_in[0];
    const int* y = (const int*)d_in[1];
    const int* xlens = (const int*)d_in[2];
    const int* ylens = (const int*)d_in[3];
    float* out = (float*)d_out;

    const size_t need_full =
        (size_t)kN * (kT / 4) * kRow * sizeof(float) + kN * sizeof(float);
    const int rows = kT * kN;

    if (ws_size >= need_full) {
        float* lpg = (float*)d_ws;
        float* nll = lpg + (size_t)kN * (kT / 4) * kRow;
        k_lse<true><<<rows / 4, 256, 0, stream>>>(logits, y, lpg, nullptr);
        k_dp_split<<<kN, 256, 0, stream>>>(lpg, y, xlens, ylens, nll);
        k_reduce<<<1, kN, 0, stream>>>(nll, out);
    } else {
        float* lsearr = (float*)d_ws;
        float* nll = lsearr + (size_t)rows;
        k_lse<false><<<rows / 4, 256, 0, stream>>>(logits, y, nullptr, lsearr);
        k_dp_fb<8><<<kN, 64, 0, stream>>>(logits, lsearr, y, xlens, ylens, nll);
        k_reduce<<<1, kN, 0, stream>>>(nll, out);
    }
}